// Round 1
// baseline (766.717 us; speedup 1.0000x reference)
//
#include <hip/hip_runtime.h>
#include <math.h>

#define DIM 512
#define NH 8
#define BLOCK 256
#define NWAVE 4

// select one of 4 compile-time-register floats by 2-bit runtime index (3 cndmask)
__device__ __forceinline__ float sel4(float a0, float a1, float a2, float a3, int k) {
  float r01 = (k & 1) ? a1 : a0;
  float r23 = (k & 1) ? a3 : a2;
  return (k & 2) ? r23 : r01;
}

__device__ __forceinline__ int lower_bound(const int* __restrict__ a, int n, int key) {
  int lo = 0, hi = n;
  while (lo < hi) {
    int mid = (lo + hi) >> 1;
    if (a[mid] < key) lo = mid + 1; else hi = mid;
  }
  return lo;
}

// One block per segment (component). component_id is sorted, so each block
// binary-searches its node range, then does a single pass over its nodes'
// features with flash-style online softmax (running m,l per head + rescaled
// pooled accumulator in registers). Raw scores are parked in the weights
// output region and normalized in-block at the end -> feats read exactly once.
__global__ __launch_bounds__(BLOCK) void seg_attn_kernel(
    const float* __restrict__ feats,
    const int* __restrict__ seg,
    const float* __restrict__ attn_w,   // [DIM][NH] row-major
    const float* __restrict__ attn_b,   // [NH]
    float* __restrict__ out,
    int N, int C, int idMode)
{
  const int c   = blockIdx.x;
  const int tid = threadIdx.x;
  const int w   = tid >> 6;     // wave id 0..3
  const int t   = tid & 63;     // lane
  const int h1  = t >> 4;       // head owning dims [4t, 4t+4)        (0..3)
  const int h2  = 4 + h1;       // head owning dims [256+4t, 256+4t+4) (4..7)

  float* pooled = out;                                   // [C][DIM]
  float* compf  = out + (size_t)C * DIM;                 // C (or 2C int64) slots
  float* wbuf   = compf + (idMode ? 2 * (size_t)C : (size_t)C);  // [N][NH]

  if (tid == 0) {
    if (idMode) ((long long*)compf)[c] = (long long)c;
    else        compf[c] = (float)c;
  }

  const int start = lower_bound(seg, N, c);
  const int end   = lower_bound(seg, N, c + 1);

  // Per-lane register slice of attn_w: rows {4t..4t+3} and {256+4t..256+4t+3},
  // each row = 8 heads = two float4. 16 float4 loads, one-time, L2-hot.
  float4 wA[4], wB[4], wC[4], wD[4];
#pragma unroll
  for (int e = 0; e < 4; ++e) {
    const float4* p0 = (const float4*)(attn_w + (size_t)(4 * t + e) * NH);
    wA[e] = p0[0];   // heads 0..3 for low-half dim
    wB[e] = p0[1];   // heads 4..7
    const float4* p1 = (const float4*)(attn_w + (size_t)(256 + 4 * t + e) * NH);
    wC[e] = p1[0];
    wD[e] = p1[1];
  }
  float bias[NH];
#pragma unroll
  for (int h = 0; h < NH; ++h) bias[h] = attn_b[h];

  const float NEG = -3.0e38f;   // finite "-inf": avoids NaN from (-inf)-(-inf)
  float m_[NH], l_[NH];
#pragma unroll
  for (int h = 0; h < NH; ++h) { m_[h] = NEG; l_[h] = 0.f; }
  float4 acc0 = make_float4(0.f, 0.f, 0.f, 0.f);
  float4 acc1 = make_float4(0.f, 0.f, 0.f, 0.f);

  for (int i = start + w; i < end; i += NWAVE) {
    const float4* fp = (const float4*)(feats + (size_t)i * DIM);
    float4 f0 = fp[t];        // dims [4t, 4t+4)       -> coalesced 1KB/inst
    float4 f1 = fp[64 + t];   // dims [256+4t, ...)

    // per-lane partial scores for all 8 heads
    float s[NH];
#pragma unroll
    for (int h = 0; h < NH; ++h) s[h] = bias[h];
    {
      const float f0e[4] = {f0.x, f0.y, f0.z, f0.w};
      const float f1e[4] = {f1.x, f1.y, f1.z, f1.w};
#pragma unroll
      for (int e = 0; e < 4; ++e) {
        s[0] = fmaf(f0e[e], wA[e].x, s[0]);
        s[1] = fmaf(f0e[e], wA[e].y, s[1]);
        s[2] = fmaf(f0e[e], wA[e].z, s[2]);
        s[3] = fmaf(f0e[e], wA[e].w, s[3]);
        s[4] = fmaf(f0e[e], wB[e].x, s[4]);
        s[5] = fmaf(f0e[e], wB[e].y, s[5]);
        s[6] = fmaf(f0e[e], wB[e].z, s[6]);
        s[7] = fmaf(f0e[e], wB[e].w, s[7]);
        s[0] = fmaf(f1e[e], wC[e].x, s[0]);
        s[1] = fmaf(f1e[e], wC[e].y, s[1]);
        s[2] = fmaf(f1e[e], wC[e].z, s[2]);
        s[3] = fmaf(f1e[e], wC[e].w, s[3]);
        s[4] = fmaf(f1e[e], wD[e].x, s[4]);
        s[5] = fmaf(f1e[e], wD[e].y, s[5]);
        s[6] = fmaf(f1e[e], wD[e].z, s[6]);
        s[7] = fmaf(f1e[e], wD[e].w, s[7]);
      }
    }
    // 64-lane butterfly: every lane ends with the full per-head scores
#pragma unroll
    for (int off = 1; off < 64; off <<= 1) {
#pragma unroll
      for (int h = 0; h < NH; ++h) s[h] += __shfl_xor(s[h], off, 64);
    }

    // park raw scores in the weights output region (normalized later in-block)
    if (t == 0) {
      float4* sp = (float4*)(wbuf + (size_t)i * NH);
      sp[0] = make_float4(s[0], s[1], s[2], s[3]);
      sp[1] = make_float4(s[4], s[5], s[6], s[7]);
    }

    // online softmax update (redundant across lanes, all-register)
    float al[NH], p[NH];
#pragma unroll
    for (int h = 0; h < NH; ++h) {
      float mn = fmaxf(m_[h], s[h]);
      al[h] = __expf(m_[h] - mn);
      p[h]  = __expf(s[h] - mn);
      l_[h] = l_[h] * al[h] + p[h];
      m_[h] = mn;
    }
    float a1 = sel4(al[0], al[1], al[2], al[3], h1);
    float p1 = sel4(p[0],  p[1],  p[2],  p[3],  h1);
    float a2 = sel4(al[4], al[5], al[6], al[7], h1);
    float p2 = sel4(p[4],  p[5],  p[6],  p[7],  h1);
    acc0.x = fmaf(p1, f0.x, acc0.x * a1);
    acc0.y = fmaf(p1, f0.y, acc0.y * a1);
    acc0.z = fmaf(p1, f0.z, acc0.z * a1);
    acc0.w = fmaf(p1, f0.w, acc0.w * a1);
    acc1.x = fmaf(p2, f1.x, acc1.x * a2);
    acc1.y = fmaf(p2, f1.y, acc1.y * a2);
    acc1.z = fmaf(p2, f1.z, acc1.z * a2);
    acc1.w = fmaf(p2, f1.w, acc1.w * a2);
  }

  // ---- cross-wave merge of (m, l) and pooled accumulators ----
  __shared__ float mlw[NWAVE][2 * NH];
  __shared__ float mf[NH], rl[NH];
  __shared__ float pool[NWAVE][DIM];   // 8 KB

  if (t == 0) {
#pragma unroll
    for (int h = 0; h < NH; ++h) { mlw[w][h] = m_[h]; mlw[w][NH + h] = l_[h]; }
  }
  __syncthreads();
  if (tid < NH) {
    float mm = NEG;
#pragma unroll
    for (int q = 0; q < NWAVE; ++q) mm = fmaxf(mm, mlw[q][tid]);
    float ll = 0.f;
#pragma unroll
    for (int q = 0; q < NWAVE; ++q) ll += mlw[q][NH + tid] * __expf(mlw[q][tid] - mm);
    mf[tid] = mm;
    rl[tid] = (ll > 0.f) ? (1.f / ll) : 0.f;   // empty segment -> 0
  }
  __syncthreads();

  float mw1 = sel4(m_[0], m_[1], m_[2], m_[3], h1);
  float mw2 = sel4(m_[4], m_[5], m_[6], m_[7], h1);
  float sc1 = __expf(mw1 - mf[h1]);   // empty wave: exp(-3e38 - finite) = 0
  float sc2 = __expf(mw2 - mf[h2]);
  float* pw = &pool[w][4 * t];
  pw[0]   = acc0.x * sc1;  pw[1]   = acc0.y * sc1;
  pw[2]   = acc0.z * sc1;  pw[3]   = acc0.w * sc1;
  pw[256] = acc1.x * sc2;  pw[257] = acc1.y * sc2;
  pw[258] = acc1.z * sc2;  pw[259] = acc1.w * sc2;
  __syncthreads();

#pragma unroll
  for (int r = 0; r < 2; ++r) {
    int d = tid + r * 256;
    float v = pool[0][d] + pool[1][d] + pool[2][d] + pool[3][d];
    v *= rl[d >> 6];
    pooled[(size_t)c * DIM + d] = v;
  }

  // normalize raw scores -> final weights (in-place, block-private range)
  for (int idx = start * NH + tid; idx < end * NH; idx += BLOCK) {
    int h = idx & 7;
    wbuf[idx] = __expf(wbuf[idx] - mf[h]) * rl[h];
  }
}

extern "C" void kernel_launch(void* const* d_in, const int* in_sizes, int n_in,
                              void* d_out, int out_size, void* d_ws, size_t ws_size,
                              hipStream_t stream) {
  const float* feats  = (const float*)d_in[0];
  const int*   seg    = (const int*)d_in[1];
  const float* attn_w = (const float*)d_in[2];
  const float* attn_b = (const float*)d_in[3];

  const int N  = in_sizes[1];            // 262144
  const int Hh = in_sizes[3];            // 8
  const int Dd = in_sizes[2] / Hh;       // 512
  long long rem = (long long)out_size - (long long)N * Hh;

  int C, idMode;
  if (rem % (Dd + 1) == 0) { C = (int)(rem / (Dd + 1)); idMode = 0; }  // comp_ids as 1 fp32 slot
  else                     { C = (int)(rem / (Dd + 2)); idMode = 1; }  // comp_ids as int64 (2 slots)

  seg_attn_kernel<<<C, BLOCK, 0, stream>>>(feats, seg, attn_w, attn_b,
                                           (float*)d_out, N, C, idMode);
}

// Round 2
// 750.659 us; speedup vs baseline: 1.0214x; 1.0214x over previous
//
#include <hip/hip_runtime.h>
#include <math.h>

#define DIM 512
#define NH 8
#define BLOCK 256
#define NWAVE 4
#define NEGF -3.0e38f   // finite "-inf": avoids NaN from (-inf)-(-inf)

// Boundary-detect: off[c] = first node index of segment c; off[C] = N.
// seg is sorted, so thread i fills off[c] for c in (seg[i], seg[i+1]].
__global__ void seg_offsets_kernel(const int* __restrict__ seg,
                                   int* __restrict__ off, int N, int C) {
  int i = blockIdx.x * blockDim.x + threadIdx.x;
  if (i >= N) return;
  int s = seg[i];
  int snext = (i + 1 < N) ? seg[i + 1] : C;
  for (int c = s + 1; c <= snext; ++c) off[c] = i + 1;
  if (i == 0) {
    for (int c = 0; c <= s; ++c) off[c] = 0;
  }
}

// select v[k] for k in 0..7 from a fully-unrolled register array (7 cndmask)
__device__ __forceinline__ float sel8(const float* v, int k) {
  float a = (k & 1) ? v[1] : v[0];
  float b = (k & 1) ? v[3] : v[2];
  float c = (k & 1) ? v[5] : v[4];
  float d = (k & 1) ? v[7] : v[6];
  float e = (k & 2) ? b : a;
  float f = (k & 2) ? d : c;
  return (k & 4) ? f : e;
}

__device__ __forceinline__ int lower_bound(const int* __restrict__ a, int n, int key) {
  int lo = 0, hi = n;
  while (lo < hi) {
    int mid = (lo + hi) >> 1;
    if (a[mid] < key) lo = mid + 1; else hi = mid;
  }
  return lo;
}

// One block per segment; flash-style online softmax, feats read exactly once.
// Lane t owns dims [8t, 8t+8) -> all in head g = t>>3 (DH=64), so each lane
// keeps ONE (m,l) pair and one alpha/p per node. Scores: per-lane partials
// over its 8 dims x 8 heads, then 3-step intra-group-of-8 butterfly, one
// bpermute transpose, 3-step final butterfly. Two nodes per iteration to
// amortize reduction latency and exp count.
__global__ __launch_bounds__(BLOCK, 2) void seg_attn_kernel(
    const float* __restrict__ feats,
    const int* __restrict__ seg,
    const float* __restrict__ attn_w,   // [DIM][NH] row-major
    const float* __restrict__ attn_b,   // [NH]
    const int* __restrict__ off,        // [C+1] or nullptr
    float* __restrict__ out,
    int N, int C, int idMode)
{
  const int c   = blockIdx.x;
  const int tid = threadIdx.x;
  const int w   = tid >> 6;     // wave id 0..3
  const int t   = tid & 63;     // lane
  const int g   = t >> 3;       // head owned by this lane
  const int j   = t & 7;        // member within 8-lane group

  float* pooled = out;                                   // [C][DIM]
  float* compf  = out + (size_t)C * DIM;                 // C (or 2C) slots
  float* wbuf   = compf + (idMode ? 2 * (size_t)C : (size_t)C);  // [N][NH]

  if (tid == 0) {
    if (idMode) ((long long*)compf)[c] = (long long)c;
    else        compf[c] = (float)c;
  }

  int start, end;
  if (off) { start = off[c]; end = off[c + 1]; }
  else     { start = lower_bound(seg, N, c); end = lower_bound(seg, N, c + 1); }

  // Per-lane weight cache: rows 8t..8t+7, all 8 heads. 16 float4 = 64 VGPRs.
  float4 w0[8], w1[8];
#pragma unroll
  for (int e = 0; e < 8; ++e) {
    const float4* p = (const float4*)(attn_w + (size_t)(8 * t + e) * NH);
    w0[e] = p[0];   // heads 0..3
    w1[e] = p[1];   // heads 4..7
  }
  const float bias_g = attn_b[g];

  float m_ = NEGF, l_ = 0.f;
  float acc[8];
#pragma unroll
  for (int e = 0; e < 8; ++e) acc[e] = 0.f;

  for (int i0 = start + 2 * w; i0 < end; i0 += 2 * NWAVE) {
    const int i1 = i0 + 1;
    const bool v1 = (i1 < end);
    const float4* r0 = (const float4*)(feats + (size_t)i0 * DIM);
    const float4* r1 = (const float4*)(feats + (size_t)(v1 ? i1 : i0) * DIM);
    // lane t covers bytes [32t, 32t+32) of each 2KB row
    float4 a0 = r0[2 * t], a1 = r0[2 * t + 1];
    float4 b0 = r1[2 * t], b1 = r1[2 * t + 1];

    float f1v[8] = {a0.x, a0.y, a0.z, a0.w, a1.x, a1.y, a1.z, a1.w};
    float f2v[8] = {b0.x, b0.y, b0.z, b0.w, b1.x, b1.y, b1.z, b1.w};

    float s1[NH], s2[NH];
#pragma unroll
    for (int h = 0; h < NH; ++h) { s1[h] = 0.f; s2[h] = 0.f; }
#pragma unroll
    for (int e = 0; e < 8; ++e) {
      s1[0] = fmaf(f1v[e], w0[e].x, s1[0]);
      s1[1] = fmaf(f1v[e], w0[e].y, s1[1]);
      s1[2] = fmaf(f1v[e], w0[e].z, s1[2]);
      s1[3] = fmaf(f1v[e], w0[e].w, s1[3]);
      s1[4] = fmaf(f1v[e], w1[e].x, s1[4]);
      s1[5] = fmaf(f1v[e], w1[e].y, s1[5]);
      s1[6] = fmaf(f1v[e], w1[e].z, s1[6]);
      s1[7] = fmaf(f1v[e], w1[e].w, s1[7]);
      s2[0] = fmaf(f2v[e], w0[e].x, s2[0]);
      s2[1] = fmaf(f2v[e], w0[e].y, s2[1]);
      s2[2] = fmaf(f2v[e], w0[e].z, s2[2]);
      s2[3] = fmaf(f2v[e], w0[e].w, s2[3]);
      s2[4] = fmaf(f2v[e], w1[e].x, s2[4]);
      s2[5] = fmaf(f2v[e], w1[e].y, s2[5]);
      s2[6] = fmaf(f2v[e], w1[e].z, s2[6]);
      s2[7] = fmaf(f2v[e], w1[e].w, s2[7]);
    }
    // intra-group-of-8 reduce: all 8 lanes of a group end with group partials
#pragma unroll
    for (int o = 1; o < 8; o <<= 1) {
#pragma unroll
      for (int h = 0; h < NH; ++h) {
        s1[h] += __shfl_xor(s1[h], o, 64);
        s2[h] += __shfl_xor(s2[h], o, 64);
      }
    }
    // transpose: lane (8g+j) fetches group j's partial for head g
    float y1 = sel8(s1, j);
    float y2 = sel8(s2, j);
    const int src = (j << 3) | g;
    y1 = __shfl(y1, src, 64);
    y2 = __shfl(y2, src, 64);
#pragma unroll
    for (int o = 1; o < 8; o <<= 1) {
      y1 += __shfl_xor(y1, o, 64);
      y2 += __shfl_xor(y2, o, 64);
    }
    y1 += bias_g;                       // full score, node i0, head g
    y2 = v1 ? (y2 + bias_g) : NEGF;     // node i1 (or masked out)

    // park raw scores: lanes j==0 write heads 0..7 -> one 32B transaction
    if (j == 0) {
      wbuf[(size_t)i0 * NH + g] = y1;
      if (v1) wbuf[(size_t)i1 * NH + g] = y2;
    }

    // online softmax update (one head per lane)
    float mn = fmaxf(m_, fmaxf(y1, y2));
    float al = __expf(m_ - mn);
    float p1 = __expf(y1 - mn);
    float p2 = __expf(y2 - mn);
    l_ = l_ * al + p1 + p2;
    m_ = mn;
#pragma unroll
    for (int e = 0; e < 8; ++e)
      acc[e] = fmaf(p2, f2v[e], fmaf(p1, f1v[e], acc[e] * al));
  }

  // ---- cross-wave merge ----
  __shared__ float mlw[NWAVE][2 * NH];
  __shared__ float mf[NH], rl[NH];
  __shared__ float pool[NWAVE][DIM];   // 8 KB

  if (j == 0) { mlw[w][g] = m_; mlw[w][NH + g] = l_; }
  __syncthreads();
  if (tid < NH) {
    float mm = NEGF;
#pragma unroll
    for (int q = 0; q < NWAVE; ++q) mm = fmaxf(mm, mlw[q][tid]);
    float ll = 0.f;
#pragma unroll
    for (int q = 0; q < NWAVE; ++q) ll += mlw[q][NH + tid] * __expf(mlw[q][tid] - mm);
    mf[tid] = mm;
    rl[tid] = (ll > 0.f) ? (1.f / ll) : 0.f;   // empty segment -> 0
  }
  __syncthreads();

  const float sc = __expf(m_ - mf[g]);   // empty wave: exp(-3e38 - x) = 0
  {
    float4* pw = (float4*)&pool[w][8 * t];
    pw[0] = make_float4(acc[0] * sc, acc[1] * sc, acc[2] * sc, acc[3] * sc);
    pw[1] = make_float4(acc[4] * sc, acc[5] * sc, acc[6] * sc, acc[7] * sc);
  }
  __syncthreads();

#pragma unroll
  for (int r = 0; r < 2; ++r) {
    int d = tid + r * 256;
    float v = pool[0][d] + pool[1][d] + pool[2][d] + pool[3][d];
    v *= rl[d >> 6];
    pooled[(size_t)c * DIM + d] = v;
  }

  // normalize parked scores -> final weights (block-private range)
  for (int idx = start * NH + tid; idx < end * NH; idx += BLOCK) {
    int h = idx & 7;
    wbuf[idx] = __expf(wbuf[idx] - mf[h]) * rl[h];
  }
}

extern "C" void kernel_launch(void* const* d_in, const int* in_sizes, int n_in,
                              void* d_out, int out_size, void* d_ws, size_t ws_size,
                              hipStream_t stream) {
  const float* feats  = (const float*)d_in[0];
  const int*   seg    = (const int*)d_in[1];
  const float* attn_w = (const float*)d_in[2];
  const float* attn_b = (const float*)d_in[3];

  const int N  = in_sizes[1];            // 262144
  const int Hh = in_sizes[3];            // 8
  const int Dd = in_sizes[2] / Hh;       // 512
  long long rem = (long long)out_size - (long long)N * Hh;

  int C, idMode;
  if (rem % (Dd + 1) == 0) { C = (int)(rem / (Dd + 1)); idMode = 0; }  // comp_ids fp32
  else                     { C = (int)(rem / (Dd + 2)); idMode = 1; }  // comp_ids int64

  int* off = nullptr;
  if (ws_size >= (size_t)(C + 1) * sizeof(int)) {
    off = (int*)d_ws;
    seg_offsets_kernel<<<(N + 255) / 256, 256, 0, stream>>>(seg, off, N, C);
  }
  seg_attn_kernel<<<C, BLOCK, 0, stream>>>(feats, seg, attn_w, attn_b, off,
                                           (float*)d_out, N, C, idMode);
}